// Round 4
// baseline (103.397 us; speedup 1.0000x reference)
//
#include <hip/hip_runtime.h>
#include <hip/hip_bf16.h>

// Problem constants (P=1 folded out everywhere)
#define NB   8      // batch
#define NA   8      // actions
#define ND   8      // dim_qk
#define NCH  64     // NA*ND q/k channels
#define GT   32     // grid T=H=W
#define KREG 216    // 6^3 halo voxels
#define IMS  40     // im2col/weight row stride in halfwords (80 B)

// LDS pool overlays (bytes):
//  build window: xS[0,2304) pad-9 rows; BTS[2304,13824); imc[13824,31744)
//  attn  window (round-17):
//    kAct[0,27648)   : 8 action-planes [216 units x 16B], unit p = n ^ (z&1)
//                      (xor-1 swizzle -> floor-rate b128 reads, audited r2)
//    vPl [27648,32256): 8 action-planes [z:96B][c':16B][8 halfs] (j=0..5 valid)
//    qU  [32256,40448): 64 vox x 8 units x 16B, unit = vox*8 + ((a^(vox>>2))&7)
//                      (r17 fix: vox>>2 = row varies across the 8-lane group ->
//                       true floor-rate b128; r16's (a^(vox&7)) was 4-way)
//    sc overlays kAct after last STEP (barrier-protected): [vox][17] float2
#define KACT_OFF 0
#define VP_OFF   27648
#define QU_OFF   32256
#define POOL_SZ  40448    // <= 40960 -> 4 blocks/CU

typedef _Float16 h2_t  __attribute__((ext_vector_type(2)));
typedef _Float16 f16x8 __attribute__((ext_vector_type(8)));
typedef float    f32x4 __attribute__((ext_vector_type(4)));

static __device__ __forceinline__ unsigned pack_h2(float a, float b) {
#if __has_builtin(__builtin_amdgcn_cvt_pkrtz)
    return __builtin_bit_cast(unsigned, __builtin_amdgcn_cvt_pkrtz(a, b));
#else
    unsigned short ha = __builtin_bit_cast(unsigned short, (_Float16)a);
    unsigned short hb = __builtin_bit_cast(unsigned short, (_Float16)b);
    return (unsigned)ha | ((unsigned)hb << 16);
#endif
}

static __device__ __forceinline__ float dot2(unsigned k, unsigned q, float c) {
#if __has_builtin(__builtin_amdgcn_fdot2)
    return __builtin_amdgcn_fdot2(__builtin_bit_cast(h2_t, k),
                                  __builtin_bit_cast(h2_t, q), c, false);
#else
    h2_t a = __builtin_bit_cast(h2_t, k), b = __builtin_bit_cast(h2_t, q);
    return c + (float)a[0] * (float)b[0] + (float)a[1] * (float)b[1];
#endif
}

// Round-17: issue-count attack. r2/r3 showed conflicts +-2M move time 0 ->
// kernel is issue/latency-bound (per-SIMD VALU issue ~60%, nothing else
// saturated). All phase-C LDS reads become immediate-offset ds_reads off 2
// precomputed xor-parity base pointers; q layout swizzle fixed (true floor).
// THREE-TIMES-CONFIRMED RULE (r9/r13): one action's state per thread.
__launch_bounds__(256, 4)
__global__ void avi_kernel(const float* __restrict__ values,
                           const float* __restrict__ rewards,
                           const float* __restrict__ w_qk,
                           const float* __restrict__ w_v,
                           float* __restrict__ out) {
    __shared__ __align__(16) char pool[POOL_SZ];
    float*    xS   = (float*)(pool + 0);        // [8][72]: z*72 + y*9 + x
    _Float16* BTSl = (_Float16*)(pool + 2304);
    _Float16* imc  = (_Float16*)(pool + 13824);
    char*     qU   = pool + QU_OFF;

    const int tid  = threadIdx.x;
    const int bb   = blockIdx.x >> 9;      // batch
    const int tile = blockIdx.x & 511;     // 8x8x8 tiles of 4^3
    const int tz = tile >> 6, ty = (tile >> 3) & 7, tx = tile & 7;
    const int g0z = tz * 4, g0y = ty * 4, g0x = tx * 4;
    const int base_in = bb * (GT * GT * GT);

    // ---- Phase A: x staging + in-block weight-image build ----
    for (int i = tid; i < 512; i += 256) {
        int lz = i >> 6, ly = (i >> 3) & 7, lx = i & 7;
        int gz = g0z + lz - 2, gy = g0y + ly - 2, gx = g0x + lx - 2;
        float v = 0.f;
        if ((unsigned)gz < 32u && (unsigned)gy < 32u && (unsigned)gx < 32u) {
            int idx = base_in + gz * 1024 + gy * 32 + gx;
            v = values[idx] + rewards[idx];
        }
        xS[lz * 72 + ly * 9 + lx] = v;
    }
    if (tid < 144) {
        float r[28];
        r[27] = 0.f;
        if (tid < 64) {
            const float* w = w_qk + (NCH + tid) * 27;
            #pragma unroll
            for (int j = 0; j < 27; ++j) r[j] = w[j];
        } else if (tid < 72) {
            int a = tid - 64;
            float m = -1e30f;
            #pragma unroll
            for (int j = 0; j < 27; ++j) { r[j] = w_v[a * 27 + j]; m = fmaxf(m, r[j]); }
            float s = 0.f;
            #pragma unroll
            for (int j = 0; j < 27; ++j) { r[j] = __expf(r[j] - m); s += r[j]; }
            float inv = 1.f / s;
            #pragma unroll
            for (int j = 0; j < 27; ++j) r[j] *= inv;
        } else if (tid < 80) {
            #pragma unroll
            for (int j = 0; j < 27; ++j) r[j] = 0.f;
        } else {
            const float* w = w_qk + (tid - 80) * 27;
            const float L2E = 1.44269504f;
            #pragma unroll
            for (int j = 0; j < 27; ++j) r[j] = w[j] * L2E;
        }
        unsigned* dst = (unsigned*)(BTSl + tid * IMS);
        #pragma unroll
        for (int p = 0; p < 14; ++p) dst[p] = pack_h2(r[2 * p], r[2 * p + 1]);
        #pragma unroll
        for (int p = 14; p < 20; ++p) dst[p] = 0u;
    }
    __syncthreads();

    // ---- Phase B1: im2col fp16 [224][IMS] (OOB voxel columns zeroed) ----
    if (tid < 224) {
        unsigned rowU[16];
        if (tid < KREG) {
            int vz = tid / 36, rem = tid - vz * 36, vy = rem / 6, vx = rem - vy * 6;
            int gz = g0z + vz - 1, gy = g0y + vy - 1, gx = g0x + vx - 1;
            float mask = ((unsigned)gz < 32u && (unsigned)gy < 32u && (unsigned)gx < 32u)
                             ? 1.f : 0.f;
            float xr[27];
            #pragma unroll
            for (int t = 0; t < 27; ++t) {
                int dz = t / 9, dy = (t / 3) % 3, dx = t % 3;
                xr[t] = xS[(vz + dz) * 72 + (vy + dy) * 9 + (vx + dx)] * mask;
            }
            #pragma unroll
            for (int p = 0; p < 13; ++p) rowU[p] = pack_h2(xr[2 * p], xr[2 * p + 1]);
            rowU[13] = pack_h2(xr[26], 0.f);
            rowU[14] = rowU[15] = 0u;
        } else {
            #pragma unroll
            for (int p = 0; p < 16; ++p) rowU[p] = 0u;
        }
        int4* dst = (int4*)((char*)imc + tid * (IMS * 2));
        dst[0] = make_int4(rowU[0], rowU[1], rowU[2], rowU[3]);
        dst[1] = make_int4(rowU[4], rowU[5], rowU[6], rowU[7]);
        dst[2] = make_int4(rowU[8], rowU[9], rowU[10], rowU[11]);
        dst[3] = make_int4(rowU[12], rowU[13], rowU[14], rowU[15]);
    }

    const int lane = tid & 63;
    const int wave = tid >> 6;
    const int quad = lane >> 4;
    const int l15  = lane & 15;

    // A-frags: A[m=l15][k=quad*8+j]; stride 40 halfs -> floor (audited)
    f16x8 af[9];
    #pragma unroll
    for (int mt = 0; mt < 9; ++mt)
        af[mt] = *(const f16x8*)(BTSl + (mt * 16 + l15) * IMS + quad * 8);

    __syncthreads();   // im2col ready

    f16x8 bf[4];
    #pragma unroll
    for (int i = 0; i < 4; ++i) {
        int nt = wave + i * 4;
        if (nt < 14)
            bf[i] = *(const f16x8*)(imc + (nt * 16 + l15) * IMS + quad * 8);
    }

    __syncthreads();   // frag loads done -> build window reusable as planes

    // ---- Phase B2: unified MFMA; k,v,q -> swizzled LDS ----
    for (int i = 0; i < 4; ++i) {
        int nt = wave + i * 4;
        if (nt >= 14) break;
        int n = nt * 16 + l15;
        bool nvalid = (n < KREG);
        int vz = n / 36, rm = n - vz * 36, vy = rm / 6, vx = rm - vy * 6;
        bool ctr = ((unsigned)(vz - 1) < 4u) && ((unsigned)(vy - 1) < 4u) &&
                   ((unsigned)(vx - 1) < 4u);
        int cvox = (vz - 1) * 16 + (vy - 1) * 4 + (vx - 1);
        // physical k unit byte offset: (n ^ (z&1)) * 16
        int kp_byte = (n * 16) ^ ((vz & 1) << 4);
        // q store helpers: slot*16 = (c16 ^ ((mt-5)<<5)) & 0x70 (disjoint bits)
        char* qw  = qU + cvox * 128 + (quad & 1) * 8;
        int   c16 = (((cvox >> 2) ^ (quad >> 1)) & 7) << 4;
        #pragma unroll
        for (int mt = 0; mt < 9; ++mt) {
            f32x4 d = __builtin_amdgcn_mfma_f32_16x16x32_f16(
                af[mt], bf[i], (f32x4){0.f, 0.f, 0.f, 0.f}, 0, 0, 0);
            if (mt < 4) {                       // k ch = mt*16 + quad*4 + reg
                if (nvalid) {
                    int a = mt * 2 + (quad >> 1);       // action plane
                    int2 w2;
                    w2.x = (int)pack_h2(d[0], d[1]);
                    w2.y = (int)pack_h2(d[2], d[3]);
                    *(int2*)(pool + KACT_OFF + a * 3456 + kp_byte + (quad & 1) * 8) = w2;
                }
            } else if (mt == 4) {               // v actions quad*4+reg (quad<2)
                if (nvalid && quad < 2) {
                    #pragma unroll
                    for (int j = 0; j < 4; ++j)
                        *(_Float16*)(pool + VP_OFF + (quad * 4 + j) * 576 +
                                     vz * 96 + vy * 16 + vx * 2) = (_Float16)d[j];
                }
            } else {                            // q ch = (mt-5)*16 + quad*4
                if (ctr) {
                    int2 w2;
                    w2.x = (int)pack_h2(d[0], d[1]);
                    w2.y = (int)pack_h2(d[2], d[3]);
                    *(int2*)(qw + ((c16 ^ ((mt - 5) << 5)) & 0x70)) = w2;
                }
            }
        }
    }
    __syncthreads();

    // ---- Phase C: 4-voxel x-run per thread, 1 action, balanced step split.
    //      All k/v reads are immediate-offset ds_reads off 3 base pointers. ----
    const int a    = (tid >> 4) & 7;      // action (wave holds 4 actions)
    const int row  = tid & 15;            // clz2*4 + cly2
    const int h    = tid >> 7;            // wave-pair half (wave-uniform!)
    const int clz2 = row >> 2, cly2 = row & 3;

    // q: one base, 4 immediate-offset b128 loads (floor-rate, r17 swizzle)
    unsigned qp[4][4];
    {
        const char* qb = qU + row * 512 + ((a ^ row) & 7) * 16;
        #pragma unroll
        for (int x = 0; x < 4; ++x) {
            const int4 qv = *(const int4*)(qb + x * 128);
            qp[x][0] = (unsigned)qv.x; qp[x][1] = (unsigned)qv.y;
            qp[x][2] = (unsigned)qv.z; qp[x][3] = (unsigned)qv.w;
        }
    }

    float ssum[4] = {0.f, 0.f, 0.f, 0.f};
    float acc[4]  = {0.f, 0.f, 0.f, 0.f};

    // xor-parity base pointers: every STEP k-load = PA/PB + compile-time imm
    const int   p   = clz2 & 1;
    const char* b0  = pool + KACT_OFF + a * 3456 + clz2 * 576 + cly2 * 96;
    const char* PAp = b0 + p * 16;
    const char* PBp = b0 + 16 - p * 16;
    const char* vb  = pool + VP_OFF + a * 576 + clz2 * 96 + cly2 * 16;

    // Full (dz,dy) step: 6 halo rows once, 12 dots. KI = DZ*576+DY*96,
    // VI = DZ*96+DY*16. PTA/PTB swap roles when DZ is odd.
#define STEP(PTA, PTB, KI, VI) do {                                           \
        int4 km[6];                                                           \
        km[0] = *(const int4*)((PTA) + (KI));                                 \
        km[1] = *(const int4*)((PTB) + (KI));                                 \
        km[2] = *(const int4*)((PTA) + (KI) + 32);                            \
        km[3] = *(const int4*)((PTB) + (KI) + 32);                            \
        km[4] = *(const int4*)((PTA) + (KI) + 64);                            \
        km[5] = *(const int4*)((PTB) + (KI) + 64);                            \
        f16x8 vv = *(const f16x8*)(vb + (VI));                                \
        float vf[6];                                                          \
        _Pragma("unroll")                                                     \
        for (int j = 0; j < 6; ++j) vf[j] = (float)vv[j];                     \
        _Pragma("unroll")                                                     \
        for (int x = 0; x < 4; ++x) {                                         \
            _Pragma("unroll")                                                 \
            for (int dx = 0; dx < 3; ++dx) {                                  \
                const int j = x + dx;                                         \
                float s = dot2((unsigned)km[j].x, qp[x][0],                   \
                          dot2((unsigned)km[j].y, qp[x][1],                   \
                          dot2((unsigned)km[j].z, qp[x][2],                   \
                          dot2((unsigned)km[j].w, qp[x][3], 0.f))));          \
                float e = exp2f(s);                                           \
                ssum[x] += e;                                                 \
                acc[x] = fmaf(e, vf[j], acc[x]);                              \
            }                                                                 \
        }                                                                     \
    } while (0)

    // Half step: x in {X0,X0+1} (X0 even), 4 rows, 6 dots.
#define HSTEP(PTA, PTB, KI, VI, X0) do {                                      \
        int4 km[4];                                                           \
        km[0] = *(const int4*)((PTA) + (KI) + (X0) * 16);                     \
        km[1] = *(const int4*)((PTB) + (KI) + (X0) * 16);                     \
        km[2] = *(const int4*)((PTA) + (KI) + (X0) * 16 + 32);                \
        km[3] = *(const int4*)((PTB) + (KI) + (X0) * 16 + 32);                \
        f16x8 vv = *(const f16x8*)(vb + (VI));                                \
        float vf[4];                                                          \
        _Pragma("unroll")                                                     \
        for (int j = 0; j < 4; ++j) vf[j] = (float)vv[(X0) + j];              \
        _Pragma("unroll")                                                     \
        for (int x = (X0); x < (X0) + 2; ++x) {                               \
            _Pragma("unroll")                                                 \
            for (int dx = 0; dx < 3; ++dx) {                                  \
                const int j = x + dx - (X0);                                  \
                float s = dot2((unsigned)km[j].x, qp[x][0],                   \
                          dot2((unsigned)km[j].y, qp[x][1],                   \
                          dot2((unsigned)km[j].z, qp[x][2],                   \
                          dot2((unsigned)km[j].w, qp[x][3], 0.f))));          \
                float e = exp2f(s);                                           \
                ssum[x] += e;                                                 \
                acc[x] = fmaf(e, vf[j], acc[x]);                              \
            }                                                                 \
        }                                                                     \
    } while (0)

    if (h == 0) {
        STEP(PAp, PBp, 0,    0);
        STEP(PAp, PBp, 96,   16);
        STEP(PAp, PBp, 192,  32);
        STEP(PBp, PAp, 576,  96);
        HSTEP(PBp, PAp, 672, 112, 0);
    } else {
        HSTEP(PBp, PAp, 672, 112, 2);
        STEP(PBp, PAp, 768,  128);
        STEP(PAp, PBp, 1152, 192);
        STEP(PAp, PBp, 1248, 208);
        STEP(PAp, PBp, 1344, 224);
    }
#undef STEP
#undef HSTEP

    // scratch overlays dead kAct region; barrier before the overlay write
    float2* sc = (float2*)pool;
    __syncthreads();
    #pragma unroll
    for (int x = 0; x < 4; ++x)
        sc[(row * 4 + x) * 17 + a * 2 + h] = make_float2(ssum[x], acc[x]);
    __syncthreads();

    // ---- merge halves, softmax-normalize, max over actions -> output ----
    if (tid < 64) {
        float best = -1e30f;
        #pragma unroll
        for (int aa = 0; aa < 8; ++aa) {
            float2 p0 = sc[tid * 17 + aa * 2 + 0];
            float2 p1 = sc[tid * 17 + aa * 2 + 1];
            best = fmaxf(best, (p0.y + p1.y) / (p0.x + p1.x));
        }
        int lz2 = tid >> 4, ly2 = (tid >> 2) & 3, lx2 = tid & 3;
        int o = base_in + (g0z + lz2) * 1024 + (g0y + ly2) * 32 + (g0x + lx2);
        out[o] = best;
    }
}

extern "C" void kernel_launch(void* const* d_in, const int* in_sizes, int n_in,
                              void* d_out, int out_size, void* d_ws, size_t ws_size,
                              hipStream_t stream) {
    const float* values  = (const float*)d_in[0];
    const float* rewards = (const float*)d_in[1];
    const float* w_qk    = (const float*)d_in[2];
    const float* w_v     = (const float*)d_in[3];
    avi_kernel<<<NB * 512, 256, 0, stream>>>(values, rewards, w_qk, w_v,
                                             (float*)d_out);
}

// Round 5
// 102.546 us; speedup vs baseline: 1.0083x; 1.0083x over previous
//
#include <hip/hip_runtime.h>
#include <hip/hip_bf16.h>

// Problem constants (P=1 folded out everywhere)
#define NB   8      // batch
#define NA   8      // actions
#define ND   8      // dim_qk
#define NCH  64     // NA*ND q/k channels
#define GT   32     // grid T=H=W
#define KREG 216    // 6^3 halo voxels
#define IMS  40     // im2col/weight row stride in halfwords (80 B)

// LDS pool overlays (bytes):
//  build window: xS[0,2304) pad-9 rows; BTS[2304,13824); imc[13824,31744)
//  attn  window (round-18):
//    kAct[0,27648)   : 8 action-planes [216 units x 16B], unit p = n ^ (z&1)
//                      (xor-1 swizzle; r18 audit: reads AND writes at floor)
//    vPl [27648,32384): 8 action-planes, stride 592B (r18: 576->592 so the
//                      action planes stop aliasing mod 128; write banks
//                      (16q+20j)%32 = 8 distinct; read stays 2-way-free)
//    qU  [32384,40576): 64 vox x 8 slots x 16B, slot s = (a ^ vox>>2 ^ vox&3)&7
//                      (r18: x enters the XOR -> q WRITES spread across the
//                       4-voxel run; reads stay floor via u0^x per 8-lane grp)
//    sc overlays kAct after last STEP (barrier-protected): [vox][17] float2
#define KACT_OFF 0
#define VP_OFF   27648
#define VSTR     592
#define QU_OFF   32384
#define POOL_SZ  40576    // <= 40960 -> 4 blocks/CU

typedef _Float16 h2_t  __attribute__((ext_vector_type(2)));
typedef _Float16 f16x8 __attribute__((ext_vector_type(8)));
typedef float    f32x4 __attribute__((ext_vector_type(4)));

static __device__ __forceinline__ unsigned pack_h2(float a, float b) {
#if __has_builtin(__builtin_amdgcn_cvt_pkrtz)
    return __builtin_bit_cast(unsigned, __builtin_amdgcn_cvt_pkrtz(a, b));
#else
    unsigned short ha = __builtin_bit_cast(unsigned short, (_Float16)a);
    unsigned short hb = __builtin_bit_cast(unsigned short, (_Float16)b);
    return (unsigned)ha | ((unsigned)hb << 16);
#endif
}

static __device__ __forceinline__ float dot2(unsigned k, unsigned q, float c) {
#if __has_builtin(__builtin_amdgcn_fdot2)
    return __builtin_amdgcn_fdot2(__builtin_bit_cast(h2_t, k),
                                  __builtin_bit_cast(h2_t, q), c, false);
#else
    h2_t a = __builtin_bit_cast(h2_t, k), b = __builtin_bit_cast(h2_t, q);
    return c + (float)a[0] * (float)b[0] + (float)a[1] * (float)b[1];
#endif
}

// Round-18: write-side bank-conflict falsification test. r2-r4 audits now
// locate ALL residual conflicts in B2's q/v stores (k-writes re-audited to be
// at floor). Fix both at zero register cost; if conflicts drop ~3x and time
// is still flat, conflicts are exonerated and r19 goes structural.
// THREE-TIMES-CONFIRMED RULE (r9/r13): one action's state per thread.
__launch_bounds__(256, 4)
__global__ void avi_kernel(const float* __restrict__ values,
                           const float* __restrict__ rewards,
                           const float* __restrict__ w_qk,
                           const float* __restrict__ w_v,
                           float* __restrict__ out) {
    __shared__ __align__(16) char pool[POOL_SZ];
    float*    xS   = (float*)(pool + 0);        // [8][72]: z*72 + y*9 + x
    _Float16* BTSl = (_Float16*)(pool + 2304);
    _Float16* imc  = (_Float16*)(pool + 13824);
    char*     qU   = pool + QU_OFF;

    const int tid  = threadIdx.x;
    const int bb   = blockIdx.x >> 9;      // batch
    const int tile = blockIdx.x & 511;     // 8x8x8 tiles of 4^3
    const int tz = tile >> 6, ty = (tile >> 3) & 7, tx = tile & 7;
    const int g0z = tz * 4, g0y = ty * 4, g0x = tx * 4;
    const int base_in = bb * (GT * GT * GT);

    // ---- Phase A: x staging + in-block weight-image build ----
    for (int i = tid; i < 512; i += 256) {
        int lz = i >> 6, ly = (i >> 3) & 7, lx = i & 7;
        int gz = g0z + lz - 2, gy = g0y + ly - 2, gx = g0x + lx - 2;
        float v = 0.f;
        if ((unsigned)gz < 32u && (unsigned)gy < 32u && (unsigned)gx < 32u) {
            int idx = base_in + gz * 1024 + gy * 32 + gx;
            v = values[idx] + rewards[idx];
        }
        xS[lz * 72 + ly * 9 + lx] = v;
    }
    if (tid < 144) {
        float r[28];
        r[27] = 0.f;
        if (tid < 64) {
            const float* w = w_qk + (NCH + tid) * 27;
            #pragma unroll
            for (int j = 0; j < 27; ++j) r[j] = w[j];
        } else if (tid < 72) {
            int a = tid - 64;
            float m = -1e30f;
            #pragma unroll
            for (int j = 0; j < 27; ++j) { r[j] = w_v[a * 27 + j]; m = fmaxf(m, r[j]); }
            float s = 0.f;
            #pragma unroll
            for (int j = 0; j < 27; ++j) { r[j] = __expf(r[j] - m); s += r[j]; }
            float inv = 1.f / s;
            #pragma unroll
            for (int j = 0; j < 27; ++j) r[j] *= inv;
        } else if (tid < 80) {
            #pragma unroll
            for (int j = 0; j < 27; ++j) r[j] = 0.f;
        } else {
            const float* w = w_qk + (tid - 80) * 27;
            const float L2E = 1.44269504f;
            #pragma unroll
            for (int j = 0; j < 27; ++j) r[j] = w[j] * L2E;
        }
        unsigned* dst = (unsigned*)(BTSl + tid * IMS);
        #pragma unroll
        for (int p = 0; p < 14; ++p) dst[p] = pack_h2(r[2 * p], r[2 * p + 1]);
        #pragma unroll
        for (int p = 14; p < 20; ++p) dst[p] = 0u;
    }
    __syncthreads();

    // ---- Phase B1: im2col fp16 [224][IMS] (OOB voxel columns zeroed) ----
    if (tid < 224) {
        unsigned rowU[16];
        if (tid < KREG) {
            int vz = tid / 36, rem = tid - vz * 36, vy = rem / 6, vx = rem - vy * 6;
            int gz = g0z + vz - 1, gy = g0y + vy - 1, gx = g0x + vx - 1;
            float mask = ((unsigned)gz < 32u && (unsigned)gy < 32u && (unsigned)gx < 32u)
                             ? 1.f : 0.f;
            float xr[27];
            #pragma unroll
            for (int t = 0; t < 27; ++t) {
                int dz = t / 9, dy = (t / 3) % 3, dx = t % 3;
                xr[t] = xS[(vz + dz) * 72 + (vy + dy) * 9 + (vx + dx)] * mask;
            }
            #pragma unroll
            for (int p = 0; p < 13; ++p) rowU[p] = pack_h2(xr[2 * p], xr[2 * p + 1]);
            rowU[13] = pack_h2(xr[26], 0.f);
            rowU[14] = rowU[15] = 0u;
        } else {
            #pragma unroll
            for (int p = 0; p < 16; ++p) rowU[p] = 0u;
        }
        int4* dst = (int4*)((char*)imc + tid * (IMS * 2));
        dst[0] = make_int4(rowU[0], rowU[1], rowU[2], rowU[3]);
        dst[1] = make_int4(rowU[4], rowU[5], rowU[6], rowU[7]);
        dst[2] = make_int4(rowU[8], rowU[9], rowU[10], rowU[11]);
        dst[3] = make_int4(rowU[12], rowU[13], rowU[14], rowU[15]);
    }

    const int lane = tid & 63;
    const int wave = tid >> 6;
    const int quad = lane >> 4;
    const int l15  = lane & 15;

    // A-frags: A[m=l15][k=quad*8+j]; stride 40 halfs -> floor (audited)
    f16x8 af[9];
    #pragma unroll
    for (int mt = 0; mt < 9; ++mt)
        af[mt] = *(const f16x8*)(BTSl + (mt * 16 + l15) * IMS + quad * 8);

    __syncthreads();   // im2col ready

    f16x8 bf[4];
    #pragma unroll
    for (int i = 0; i < 4; ++i) {
        int nt = wave + i * 4;
        if (nt < 14)
            bf[i] = *(const f16x8*)(imc + (nt * 16 + l15) * IMS + quad * 8);
    }

    __syncthreads();   // frag loads done -> build window reusable as planes

    // ---- Phase B2: unified MFMA; k,v,q -> swizzled LDS ----
    for (int i = 0; i < 4; ++i) {
        int nt = wave + i * 4;
        if (nt >= 14) break;
        int n = nt * 16 + l15;
        bool nvalid = (n < KREG);
        int vz = n / 36, rm = n - vz * 36, vy = rm / 6, vx = rm - vy * 6;
        bool ctr = ((unsigned)(vz - 1) < 4u) && ((unsigned)(vy - 1) < 4u) &&
                   ((unsigned)(vx - 1) < 4u);
        int cvox = (vz - 1) * 16 + (vy - 1) * 4 + (vx - 1);
        // physical k unit byte offset: (n ^ (z&1)) * 16
        int kp_byte = (n * 16) ^ ((vz & 1) << 4);
        // q store base: slot s = (a ^ cvox>>2 ^ cvox&3)&7 with a=(mt-5)*2+qh;
        // (mt-5)<<1 XORs in via addr ^ ((mt-5)<<5) (disjoint bits 5-6)
        int qoff = cvox * 128 +
                   ((((quad >> 1) ^ (cvox >> 2) ^ (cvox & 3)) & 7) << 4) +
                   (quad & 1) * 8;
        #pragma unroll
        for (int mt = 0; mt < 9; ++mt) {
            f32x4 d = __builtin_amdgcn_mfma_f32_16x16x32_f16(
                af[mt], bf[i], (f32x4){0.f, 0.f, 0.f, 0.f}, 0, 0, 0);
            if (mt < 4) {                       // k ch = mt*16 + quad*4 + reg
                if (nvalid) {
                    int a = mt * 2 + (quad >> 1);       // action plane
                    int2 w2;
                    w2.x = (int)pack_h2(d[0], d[1]);
                    w2.y = (int)pack_h2(d[2], d[3]);
                    *(int2*)(pool + KACT_OFF + a * 3456 + kp_byte + (quad & 1) * 8) = w2;
                }
            } else if (mt == 4) {               // v actions quad*4+reg (quad<2)
                if (nvalid && quad < 2) {
                    #pragma unroll
                    for (int j = 0; j < 4; ++j)
                        *(_Float16*)(pool + VP_OFF + (quad * 4 + j) * VSTR +
                                     vz * 96 + vy * 16 + vx * 2) = (_Float16)d[j];
                }
            } else {                            // q ch = (mt-5)*16 + quad*4
                if (ctr) {
                    int2 w2;
                    w2.x = (int)pack_h2(d[0], d[1]);
                    w2.y = (int)pack_h2(d[2], d[3]);
                    *(int2*)(qU + (qoff ^ ((mt - 5) << 5))) = w2;
                }
            }
        }
    }
    __syncthreads();

    // ---- Phase C: 4-voxel x-run per thread, 1 action, balanced step split.
    //      All k/v reads are immediate-offset ds_reads off 3 base pointers. ----
    const int a    = (tid >> 4) & 7;      // action (wave holds 4 actions)
    const int row  = tid & 15;            // clz2*4 + cly2
    const int h    = tid >> 7;            // wave-pair half (wave-uniform!)
    const int clz2 = row >> 2, cly2 = row & 3;

    // q: 4 b128 loads, slot = u0^x (floor-rate: u0=(a^row)&7 varies per lane)
    unsigned qp[4][4];
    {
        const char* qb = qU + row * 512;
        const int   u0 = (a ^ row) & 7;
        #pragma unroll
        for (int x = 0; x < 4; ++x) {
            const int4 qv = *(const int4*)(qb + x * 128 + ((u0 ^ x) << 4));
            qp[x][0] = (unsigned)qv.x; qp[x][1] = (unsigned)qv.y;
            qp[x][2] = (unsigned)qv.z; qp[x][3] = (unsigned)qv.w;
        }
    }

    float ssum[4] = {0.f, 0.f, 0.f, 0.f};
    float acc[4]  = {0.f, 0.f, 0.f, 0.f};

    // xor-parity base pointers: every STEP k-load = PA/PB + compile-time imm
    const int   p   = clz2 & 1;
    const char* b0  = pool + KACT_OFF + a * 3456 + clz2 * 576 + cly2 * 96;
    const char* PAp = b0 + p * 16;
    const char* PBp = b0 + 16 - p * 16;
    const char* vb  = pool + VP_OFF + a * VSTR + clz2 * 96 + cly2 * 16;

    // Full (dz,dy) step: 6 halo rows once, 12 dots. KI = DZ*576+DY*96,
    // VI = DZ*96+DY*16. PTA/PTB swap roles when DZ is odd.
#define STEP(PTA, PTB, KI, VI) do {                                           \
        int4 km[6];                                                           \
        km[0] = *(const int4*)((PTA) + (KI));                                 \
        km[1] = *(const int4*)((PTB) + (KI));                                 \
        km[2] = *(const int4*)((PTA) + (KI) + 32);                            \
        km[3] = *(const int4*)((PTB) + (KI) + 32);                            \
        km[4] = *(const int4*)((PTA) + (KI) + 64);                            \
        km[5] = *(const int4*)((PTB) + (KI) + 64);                            \
        f16x8 vv = *(const f16x8*)(vb + (VI));                                \
        float vf[6];                                                          \
        _Pragma("unroll")                                                     \
        for (int j = 0; j < 6; ++j) vf[j] = (float)vv[j];                     \
        _Pragma("unroll")                                                     \
        for (int x = 0; x < 4; ++x) {                                         \
            _Pragma("unroll")                                                 \
            for (int dx = 0; dx < 3; ++dx) {                                  \
                const int j = x + dx;                                         \
                float s = dot2((unsigned)km[j].x, qp[x][0],                   \
                          dot2((unsigned)km[j].y, qp[x][1],                   \
                          dot2((unsigned)km[j].z, qp[x][2],                   \
                          dot2((unsigned)km[j].w, qp[x][3], 0.f))));          \
                float e = exp2f(s);                                           \
                ssum[x] += e;                                                 \
                acc[x] = fmaf(e, vf[j], acc[x]);                              \
            }                                                                 \
        }                                                                     \
    } while (0)

    // Half step: x in {X0,X0+1} (X0 even), 4 rows, 6 dots.
#define HSTEP(PTA, PTB, KI, VI, X0) do {                                      \
        int4 km[4];                                                           \
        km[0] = *(const int4*)((PTA) + (KI) + (X0) * 16);                     \
        km[1] = *(const int4*)((PTB) + (KI) + (X0) * 16);                     \
        km[2] = *(const int4*)((PTA) + (KI) + (X0) * 16 + 32);                \
        km[3] = *(const int4*)((PTB) + (KI) + (X0) * 16 + 32);                \
        f16x8 vv = *(const f16x8*)(vb + (VI));                                \
        float vf[4];                                                          \
        _Pragma("unroll")                                                     \
        for (int j = 0; j < 4; ++j) vf[j] = (float)vv[(X0) + j];              \
        _Pragma("unroll")                                                     \
        for (int x = (X0); x < (X0) + 2; ++x) {                               \
            _Pragma("unroll")                                                 \
            for (int dx = 0; dx < 3; ++dx) {                                  \
                const int j = x + dx - (X0);                                  \
                float s = dot2((unsigned)km[j].x, qp[x][0],                   \
                          dot2((unsigned)km[j].y, qp[x][1],                   \
                          dot2((unsigned)km[j].z, qp[x][2],                   \
                          dot2((unsigned)km[j].w, qp[x][3], 0.f))));          \
                float e = exp2f(s);                                           \
                ssum[x] += e;                                                 \
                acc[x] = fmaf(e, vf[j], acc[x]);                              \
            }                                                                 \
        }                                                                     \
    } while (0)

    if (h == 0) {
        STEP(PAp, PBp, 0,    0);
        STEP(PAp, PBp, 96,   16);
        STEP(PAp, PBp, 192,  32);
        STEP(PBp, PAp, 576,  96);
        HSTEP(PBp, PAp, 672, 112, 0);
    } else {
        HSTEP(PBp, PAp, 672, 112, 2);
        STEP(PBp, PAp, 768,  128);
        STEP(PAp, PBp, 1152, 192);
        STEP(PAp, PBp, 1248, 208);
        STEP(PAp, PBp, 1344, 224);
    }
#undef STEP
#undef HSTEP

    // scratch overlays dead kAct region; barrier before the overlay write
    float2* sc = (float2*)pool;
    __syncthreads();
    #pragma unroll
    for (int x = 0; x < 4; ++x)
        sc[(row * 4 + x) * 17 + a * 2 + h] = make_float2(ssum[x], acc[x]);
    __syncthreads();

    // ---- merge halves, softmax-normalize, max over actions -> output ----
    if (tid < 64) {
        float best = -1e30f;
        #pragma unroll
        for (int aa = 0; aa < 8; ++aa) {
            float2 p0 = sc[tid * 17 + aa * 2 + 0];
            float2 p1 = sc[tid * 17 + aa * 2 + 1];
            best = fmaxf(best, (p0.y + p1.y) / (p0.x + p1.x));
        }
        int lz2 = tid >> 4, ly2 = (tid >> 2) & 3, lx2 = tid & 3;
        int o = base_in + (g0z + lz2) * 1024 + (g0y + ly2) * 32 + (g0x + lx2);
        out[o] = best;
    }
}

extern "C" void kernel_launch(void* const* d_in, const int* in_sizes, int n_in,
                              void* d_out, int out_size, void* d_ws, size_t ws_size,
                              hipStream_t stream) {
    const float* values  = (const float*)d_in[0];
    const float* rewards = (const float*)d_in[1];
    const float* w_qk    = (const float*)d_in[2];
    const float* w_v     = (const float*)d_in[3];
    avi_kernel<<<NB * 512, 256, 0, stream>>>(values, rewards, w_qk, w_v,
                                             (float*)d_out);
}